// Round 4
// baseline (212.637 us; speedup 1.0000x reference)
//
#include <hip/hip_runtime.h>
#include <hip/hip_bf16.h>

// HT layer via bf16 32x32x16 MFMA.
//   Y[b] = sum_p A_p(64x64) @ X_b(64x64) @ W_p(64x64) + bias
// Step A: T^T[kl][ac] = sum_ij X^T[kl][ij] * A_p^T[ij][ac]   (A=X^T frag, B=AF)
// Step B: Y[ac][de]  += sum_kl T[ac][kl]  * W_p[kl][de]      (A=tb repack, B=WF)
// mfma_f32_32x32x16_bf16 layouts:
//   A: A[m=lane&31][k=(lane>>5)*8+j]   B: B[k=(lane>>5)*8+j][n=lane&31]
//   C/D: col=lane&31, row=(reg&3)+8*(reg>>2)+4*(lane>>5)
// Step-A C/D -> step-B A-operand repack: 8 v_cvt_pk_bf16_f32 +
// 4 v_permlane32_swap per tile, fully in-register (proven rounds 1-3).
// Structure (phase-overlap design, round-3 intent with the spill fixed):
//   grid 256 blocks x 512 thr (8 waves), 1 block/CU (144KB LDS), NB=2.
//   Block start: stage ALL frags (128KB) + bias (16KB) into LDS once.
//   Main loop: pure ds_read+MFMA, no vmem, no barriers.
//   Next-batch x loads are issued AFTER the p-loop and drain under the
//   64 epilogue stores, so xn[64] never overlaps the MFMA working set.
//   Register budget: p-loop peak ~196, epilogue ~148 -> fits 256 (2 waves/EU).
//   amdgpu_waves_per_eu(2,2) pins the allocator to that occupancy (round 3
//   regression: allocator chose 128 VGPRs for unreachable occupancy and
//   spilled ~60 regs -> +93MB scratch writes, 2.4x slowdown).

typedef short bf16x8 __attribute__((ext_vector_type(8)));
typedef float f32x16 __attribute__((ext_vector_type(16)));

union Frag8 {
    bf16x8 v;
    unsigned int u4[4];
};

static __device__ __forceinline__ unsigned int pkbf(float a, float b) {
    // v_cvt_pk_bf16_f32 on gfx950 (RNE), a -> low 16, b -> high 16
    __hip_bfloat162 h = __float22bfloat162_rn(float2{a, b});
    return *reinterpret_cast<unsigned int*>(&h);
}

// ---------------------------------------------------------------------------
// Precompute bf16 fragments of A_p^T (step-A B-operand) and W_p (step-B
// B-operand). One block per (isW, p); two-stage contraction in LDS.
// Layout: frags[isW][p(8)][t(2)][kc(4)][lane(64)][j(8)] bf16, 64KB each half.
//   contraction index k = kc*16 + (lane>>5)*8 + j   (ij for AF, kl for WF)
//   other index       n = t*32 + (lane&31)          (ac for AF, de for WF)
// AF element = WL[ij][ac][p],  WF element = WR[kl][de][p]
// ---------------------------------------------------------------------------
__global__ __launch_bounds__(256) void ht_precompute(
        const float* __restrict__ F0, const float* __restrict__ F1,
        const float* __restrict__ F2, const float* __restrict__ F3,
        const float* __restrict__ CL, const float* __restrict__ CR,
        unsigned short* __restrict__ frags) {
    __shared__ float sFa[512], sFb[512], sC[512], sG[512];
    const int isW = blockIdx.x >> 3;
    const int p   = blockIdx.x & 7;
    const float* Fa = isW ? F2 : F0;   // (in, out, rank) = 8x8x8
    const float* Fb = isW ? F3 : F1;
    const float* C  = isW ? CR : CL;   // (r, s, p) = 8x8x8
    const int tid = threadIdx.x;

    for (int u = tid; u < 512; u += 256) {
        sFa[u] = Fa[u]; sFb[u] = Fb[u]; sC[u] = C[u];
    }
    __syncthreads();

    // stage 1: G[r][jc] = sum_s Fb[jc*8+s] * C[(r*8+s)*8+p]   (512 entries)
#pragma unroll
    for (int e = 0; e < 2; ++e) {
        int u = tid + e * 256;
        int r = u >> 6, jc = u & 63;
        float acc = 0.f;
#pragma unroll
        for (int s = 0; s < 8; ++s)
            acc += sFb[jc * 8 + s] * sC[(r * 8 + s) * 8 + p];
        sG[u] = acc;   // sG[r*64 + jc]
    }
    __syncthreads();

    // stage 2: out[k=i1*8+j][n] = sum_r Fa[(i1*8+a)*8+r] * G[r][j*8+c]
#pragma unroll
    for (int e = 0; e < 2; ++e) {
        int g  = tid + e * 256;
        int i1 = g >> 6, n = g & 63;
        int a  = n >> 3, c = n & 7;
        float fa[8];
#pragma unroll
        for (int r = 0; r < 8; ++r) fa[r] = sFa[(i1 * 8 + a) * 8 + r];
        unsigned int pk[4];
#pragma unroll
        for (int jp = 0; jp < 4; ++jp) {
            float o0 = 0.f, o1 = 0.f;
#pragma unroll
            for (int r = 0; r < 8; ++r) {
                o0 += fa[r] * sG[r * 64 + (2 * jp) * 8 + c];
                o1 += fa[r] * sG[r * 64 + (2 * jp + 1) * 8 + c];
            }
            pk[jp] = pkbf(o0, o1);
        }
        int t = n >> 5, kc = i1 >> 1, lane_ = (i1 & 1) * 32 + (n & 31);
        unsigned int* dst = (unsigned int*)(frags + (size_t)isW * 32768 +
                                            ((((p * 2 + t) * 4 + kc) << 6) + lane_) * 8);
        *(uint4*)dst = uint4{pk[0], pk[1], pk[2], pk[3]};
    }
}

#define NB 2   // batches per wave

__global__ __launch_bounds__(512)
__attribute__((amdgpu_waves_per_eu(2, 2)))
void ht_main(const float* __restrict__ x,
             const unsigned short* __restrict__ frags,
             const float* __restrict__ bias,
             float* __restrict__ out) {
    // LDS: [0,64K) AF all p | [64K,128K) WF all p | [128K,144K) bias
    __shared__ __align__(16) char smem[147456];
    const int tid  = threadIdx.x;
    const int lane = tid & 63;
    const int w    = __builtin_amdgcn_readfirstlane(tid >> 6);  // wave 0..7
    const int l31  = lane & 31;
    const int hi   = lane >> 5;
    const int b0   = blockIdx.x * (8 * NB) + w * NB;

    // ---- prologue: issue x loads for batch 0 (drain under the staging wait)
    float xr[64];   // xr[(rb*4+kc)*8 + j] = X^T[kl=rb*32+l31][ij=kc*16+hi*8+j]
    {
        const float* xb = x + ((size_t)b0 << 12);
#pragma unroll
        for (int rb = 0; rb < 2; ++rb)
#pragma unroll
            for (int kc = 0; kc < 4; ++kc)
#pragma unroll
                for (int j = 0; j < 8; ++j)
                    xr[(rb * 4 + kc) * 8 + j] = xb[(kc * 16 + hi * 8 + j) * 64 + rb * 32 + l31];
    }
    // ---- stage frags (128KB) + bias (16KB) into LDS, once per block
#pragma unroll
    for (int r = 0; r < 16; ++r)
        __builtin_amdgcn_global_load_lds(
            (const __attribute__((address_space(1))) void*)((const char*)frags + r * 8192 + tid * 16),
            (__attribute__((address_space(3))) void*)(smem + r * 8192 + tid * 16), 16, 0, 0);
#pragma unroll
    for (int r = 0; r < 2; ++r)
        __builtin_amdgcn_global_load_lds(
            (const __attribute__((address_space(1))) void*)((const char*)bias + r * 8192 + tid * 16),
            (__attribute__((address_space(3))) void*)(smem + 131072 + r * 8192 + tid * 16), 16, 0, 0);
    __syncthreads();   // drains vmcnt (incl. x loads) + syncs waves; the only barrier

    const unsigned short* LA = (const unsigned short*)smem;             // AF, elements
    const unsigned short* LW = (const unsigned short*)(smem + 65536);   // WF
    const float* sBias = (const float*)(smem + 131072);

    // ---- convert batch-0 xf (xr dies here; never live during a p-loop)
    Frag8 xf[2][4];
#pragma unroll
    for (int rb = 0; rb < 2; ++rb)
#pragma unroll
        for (int kc = 0; kc < 4; ++kc)
#pragma unroll
            for (int jp = 0; jp < 4; ++jp)
                xf[rb][kc].u4[jp] = pkbf(xr[(rb * 4 + kc) * 8 + 2 * jp],
                                         xr[(rb * 4 + kc) * 8 + 2 * jp + 1]);

#pragma unroll 1
    for (int i = 0; i < NB; ++i) {
        const int b = b0 + i;

        f32x16 acc[2][2];   // Y tiles: [cb over ac][nb2 over de]
#pragma unroll
        for (int a = 0; a < 2; ++a)
#pragma unroll
            for (int c = 0; c < 2; ++c)
#pragma unroll
                for (int e = 0; e < 16; ++e)
                    acc[a][c][e] = 0.f;

        // ---- p-loop: pure LDS reads + MFMA + VALU repack. No vmem, no barriers.
#pragma unroll 1
        for (int p = 0; p < 8; ++p) {
            Frag8 af[2][4];
#pragma unroll
            for (int t = 0; t < 2; ++t)
#pragma unroll
                for (int kc = 0; kc < 4; ++kc)
                    af[t][kc].v = *(const bf16x8*)(LA + p * 4096 + ((t * 4 + kc) * 64 + lane) * 8);
#pragma unroll
            for (int rb = 0; rb < 2; ++rb) {       // rb: kl block (contraction of step B)
                Frag8 wfr[2][2];                   // wf[nb2][kk = 2rb, 2rb+1]
#pragma unroll
                for (int t = 0; t < 2; ++t)
#pragma unroll
                    for (int kk = 0; kk < 2; ++kk)
                        wfr[t][kk].v = *(const bf16x8*)(LW + p * 4096 + ((t * 4 + 2 * rb + kk) * 64 + lane) * 8);
#pragma unroll
                for (int cb = 0; cb < 2; ++cb) {   // cb: ac block
                    // ---- Step A: T^T tile (kl rows rb*32.., ac cols cb*32..)
                    f32x16 t;
#pragma unroll
                    for (int e = 0; e < 16; ++e) t[e] = 0.f;
#pragma unroll
                    for (int kc = 0; kc < 4; ++kc)
                        t = __builtin_amdgcn_mfma_f32_32x32x16_bf16(xf[rb][kc].v, af[cb][kc].v, t, 0, 0, 0);
                    // ---- Repack C/D -> two step-B A-operand frags, in-register.
                    unsigned int wd[8];
#pragma unroll
                    for (int h = 0; h < 8; ++h) wd[h] = pkbf(t[2 * h], t[2 * h + 1]);
                    auto s02 = __builtin_amdgcn_permlane32_swap(wd[0], wd[2], false, false);
                    auto s13 = __builtin_amdgcn_permlane32_swap(wd[1], wd[3], false, false);
                    auto s46 = __builtin_amdgcn_permlane32_swap(wd[4], wd[6], false, false);
                    auto s57 = __builtin_amdgcn_permlane32_swap(wd[5], wd[7], false, false);
                    Frag8 tb0, tb1;
                    tb0.u4[0] = s02[0]; tb0.u4[1] = s13[0]; tb0.u4[2] = s02[1]; tb0.u4[3] = s13[1];
                    tb1.u4[0] = s46[0]; tb1.u4[1] = s57[0]; tb1.u4[2] = s46[1]; tb1.u4[3] = s57[1];
                    // ---- Step B: Y[ac][de] += T[ac][kl] * W[kl][de]
                    acc[cb][0] = __builtin_amdgcn_mfma_f32_32x32x16_bf16(tb0.v, wfr[0][0].v, acc[cb][0], 0, 0, 0);
                    acc[cb][0] = __builtin_amdgcn_mfma_f32_32x32x16_bf16(tb1.v, wfr[0][1].v, acc[cb][0], 0, 0, 0);
                    acc[cb][1] = __builtin_amdgcn_mfma_f32_32x32x16_bf16(tb0.v, wfr[1][0].v, acc[cb][1], 0, 0, 0);
                    acc[cb][1] = __builtin_amdgcn_mfma_f32_32x32x16_bf16(tb1.v, wfr[1][1].v, acc[cb][1], 0, 0, 0);
                }
            }
        }

        // ---- Issue next batch's x loads NOW: they drain under the 64 store
        // instructions below (loads precede stores in vmcnt order), and xn only
        // overlaps the dying acc -- not the p-loop working set.
        float xn[64];
        if (i + 1 < NB) {
            const float* xb = x + ((size_t)(b + 1) << 12);
#pragma unroll
            for (int rb = 0; rb < 2; ++rb)
#pragma unroll
                for (int kc = 0; kc < 4; ++kc)
#pragma unroll
                    for (int j = 0; j < 8; ++j)
                        xn[(rb * 4 + kc) * 8 + j] = xb[(kc * 16 + hi * 8 + j) * 64 + rb * 32 + l31];
        }

        // ---- Epilogue: direct coalesced stores. C/D: col de = nb2*32+l31,
        // row ac = cb*32 + (r&3)+8*(r>>2)+4*hi. Bias from LDS (lgkm, not vmcnt).
        float* ob = out + ((size_t)b << 12);
#pragma unroll
        for (int cb = 0; cb < 2; ++cb)
#pragma unroll
            for (int nb2 = 0; nb2 < 2; ++nb2)
#pragma unroll
                for (int r = 0; r < 16; ++r) {
                    int ac = cb * 32 + (r & 3) + 8 * (r >> 2) + 4 * hi;
                    int o  = ac * 64 + nb2 * 32 + l31;
                    ob[o] = acc[cb][nb2][r] + sBias[o];
                }

        // ---- Convert next batch's xf (compiler waits on xn loads here,
        // after the stores were issued).
        if (i + 1 < NB) {
#pragma unroll
            for (int rb = 0; rb < 2; ++rb)
#pragma unroll
                for (int kc = 0; kc < 4; ++kc)
#pragma unroll
                    for (int jp = 0; jp < 4; ++jp)
                        xf[rb][kc].u4[jp] = pkbf(xn[(rb * 4 + kc) * 8 + 2 * jp],
                                                 xn[(rb * 4 + kc) * 8 + 2 * jp + 1]);
        }
    }
}

extern "C" void kernel_launch(void* const* d_in, const int* in_sizes, int n_in,
                              void* d_out, int out_size, void* d_ws, size_t ws_size,
                              hipStream_t stream) {
    const float* x    = (const float*)d_in[0];
    const float* F0   = (const float*)d_in[1];
    const float* F1   = (const float*)d_in[2];
    const float* F2   = (const float*)d_in[3];
    const float* F3   = (const float*)d_in[4];
    const float* CL   = (const float*)d_in[5];
    const float* CR   = (const float*)d_in[6];
    const float* bias = (const float*)d_in[7];
    float* out = (float*)d_out;
    unsigned short* frags = (unsigned short*)d_ws;   // 128 KB

    const int B = in_sizes[0] / 4096;   // 4096

    ht_precompute<<<16, 256, 0, stream>>>(F0, F1, F2, F3, CL, CR, frags);
    ht_main<<<B / (8 * NB), 512, 0, stream>>>(x, frags, bias, out);
}

// Round 5
// 149.212 us; speedup vs baseline: 1.4251x; 1.4251x over previous
//
#include <hip/hip_runtime.h>
#include <hip/hip_bf16.h>

// HT layer via bf16 32x32x16 MFMA.
//   Y[b] = sum_p A_p(64x64) @ X_b(64x64) @ W_p(64x64) + bias
// Step A: T^T[kl][ac] = sum_ij X^T[kl][ij] * A_p^T[ij][ac]   (A=X^T frag, B=AF)
// Step B: Y[ac][de]  += sum_kl T[ac][kl]  * W_p[kl][de]      (A=tb repack, B=WF)
// mfma_f32_32x32x16_bf16 layouts:
//   A: A[m=lane&31][k=(lane>>5)*8+j]   B: B[k=(lane>>5)*8+j][n=lane&31]
//   C/D: col=lane&31, row=(reg&3)+8*(reg>>2)+4*(lane>>5)
// Step-A C/D -> step-B A-operand repack: 8 v_cvt_pk_bf16_f32 +
// 4 v_permlane32_swap per tile, fully in-register (proven rounds 1-4).
// Structure:
//   grid 512 blocks x 512 thr (8 waves), 1 block/CU (144KB LDS), 1 batch/wave.
//   Block start: stage ALL frags (128KB) + bias (16KB) into LDS once; one
//   __syncthreads. Main loop: pure ds_read+MFMA, no vmem, no barriers.
//   Two dispatch rounds (512 blocks / 256 CU) stagger phases across the CU.
// Register budget (the round-3/4 lesson): the compiler pins this kernel at
// 128 arch-VGPR + AGPRs and spills anything past it (+96MB scratch writes).
// NB=1 removes the 64-float prefetch array -> p-loop VGPR side ~110,
// AGPR side (acc 64 + t 16) = 80 -> fits 128/128 with zero spill.

typedef short bf16x8 __attribute__((ext_vector_type(8)));
typedef float f32x16 __attribute__((ext_vector_type(16)));

union Frag8 {
    bf16x8 v;
    unsigned int u4[4];
};

static __device__ __forceinline__ unsigned int pkbf(float a, float b) {
    // v_cvt_pk_bf16_f32 on gfx950 (RNE), a -> low 16, b -> high 16
    __hip_bfloat162 h = __float22bfloat162_rn(float2{a, b});
    return *reinterpret_cast<unsigned int*>(&h);
}

// ---------------------------------------------------------------------------
// Precompute bf16 fragments of A_p^T (step-A B-operand) and W_p (step-B
// B-operand). One block per (isW, p); two-stage contraction in LDS.
// Layout: frags[isW][p(8)][t(2)][kc(4)][lane(64)][j(8)] bf16, 64KB each half.
//   contraction index k = kc*16 + (lane>>5)*8 + j   (ij for AF, kl for WF)
//   other index       n = t*32 + (lane&31)          (ac for AF, de for WF)
// AF element = WL[ij][ac][p],  WF element = WR[kl][de][p]
// ---------------------------------------------------------------------------
__global__ __launch_bounds__(256) void ht_precompute(
        const float* __restrict__ F0, const float* __restrict__ F1,
        const float* __restrict__ F2, const float* __restrict__ F3,
        const float* __restrict__ CL, const float* __restrict__ CR,
        unsigned short* __restrict__ frags) {
    __shared__ float sFa[512], sFb[512], sC[512], sG[512];
    const int isW = blockIdx.x >> 3;
    const int p   = blockIdx.x & 7;
    const float* Fa = isW ? F2 : F0;   // (in, out, rank) = 8x8x8
    const float* Fb = isW ? F3 : F1;
    const float* C  = isW ? CR : CL;   // (r, s, p) = 8x8x8
    const int tid = threadIdx.x;

    for (int u = tid; u < 512; u += 256) {
        sFa[u] = Fa[u]; sFb[u] = Fb[u]; sC[u] = C[u];
    }
    __syncthreads();

    // stage 1: G[r][jc] = sum_s Fb[jc*8+s] * C[(r*8+s)*8+p]   (512 entries)
#pragma unroll
    for (int e = 0; e < 2; ++e) {
        int u = tid + e * 256;
        int r = u >> 6, jc = u & 63;
        float acc = 0.f;
#pragma unroll
        for (int s = 0; s < 8; ++s)
            acc += sFb[jc * 8 + s] * sC[(r * 8 + s) * 8 + p];
        sG[u] = acc;   // sG[r*64 + jc]
    }
    __syncthreads();

    // stage 2: out[k=i1*8+j][n] = sum_r Fa[(i1*8+a)*8+r] * G[r][j*8+c]
#pragma unroll
    for (int e = 0; e < 2; ++e) {
        int g  = tid + e * 256;
        int i1 = g >> 6, n = g & 63;
        int a  = n >> 3, c = n & 7;
        float fa[8];
#pragma unroll
        for (int r = 0; r < 8; ++r) fa[r] = sFa[(i1 * 8 + a) * 8 + r];
        unsigned int pk[4];
#pragma unroll
        for (int jp = 0; jp < 4; ++jp) {
            float o0 = 0.f, o1 = 0.f;
#pragma unroll
            for (int r = 0; r < 8; ++r) {
                o0 += fa[r] * sG[r * 64 + (2 * jp) * 8 + c];
                o1 += fa[r] * sG[r * 64 + (2 * jp + 1) * 8 + c];
            }
            pk[jp] = pkbf(o0, o1);
        }
        int t = n >> 5, kc = i1 >> 1, lane_ = (i1 & 1) * 32 + (n & 31);
        unsigned int* dst = (unsigned int*)(frags + (size_t)isW * 32768 +
                                            ((((p * 2 + t) * 4 + kc) << 6) + lane_) * 8);
        *(uint4*)dst = uint4{pk[0], pk[1], pk[2], pk[3]};
    }
}

__global__ __launch_bounds__(512) void ht_main(const float* __restrict__ x,
                                               const unsigned short* __restrict__ frags,
                                               const float* __restrict__ bias,
                                               float* __restrict__ out) {
    // LDS: [0,64K) AF all p | [64K,128K) WF all p | [128K,144K) bias
    __shared__ __align__(16) char smem[147456];
    const int tid  = threadIdx.x;
    const int lane = tid & 63;
    const int w    = __builtin_amdgcn_readfirstlane(tid >> 6);  // wave 0..7
    const int l31  = lane & 31;
    const int hi   = lane >> 5;
    const int b    = blockIdx.x * 8 + w;                        // 1 batch/wave

    // ---- issue x loads first (oldest in vmcnt; drain under the staging wait)
    float xr[64];   // xr[(rb*4+kc)*8 + j] = X^T[kl=rb*32+l31][ij=kc*16+hi*8+j]
    {
        const float* xb = x + ((size_t)b << 12);
#pragma unroll
        for (int rb = 0; rb < 2; ++rb)
#pragma unroll
            for (int kc = 0; kc < 4; ++kc)
#pragma unroll
                for (int j = 0; j < 8; ++j)
                    xr[(rb * 4 + kc) * 8 + j] = xb[(kc * 16 + hi * 8 + j) * 64 + rb * 32 + l31];
    }
    // ---- stage frags (128KB) + bias (16KB) into LDS, once per block
#pragma unroll
    for (int r = 0; r < 16; ++r)
        __builtin_amdgcn_global_load_lds(
            (const __attribute__((address_space(1))) void*)((const char*)frags + r * 8192 + tid * 16),
            (__attribute__((address_space(3))) void*)(smem + r * 8192 + tid * 16), 16, 0, 0);
#pragma unroll
    for (int r = 0; r < 2; ++r)
        __builtin_amdgcn_global_load_lds(
            (const __attribute__((address_space(1))) void*)((const char*)bias + r * 8192 + tid * 16),
            (__attribute__((address_space(3))) void*)(smem + 131072 + r * 8192 + tid * 16), 16, 0, 0);
    __syncthreads();   // drains vmcnt (incl. x loads) + syncs waves; the only barrier

    const unsigned short* LA = (const unsigned short*)smem;             // AF, elements
    const unsigned short* LW = (const unsigned short*)(smem + 65536);   // WF
    const float* sBias = (const float*)(smem + 131072);

    // ---- convert xf (xr dies here; never live during the p-loop)
    Frag8 xf[2][4];
#pragma unroll
    for (int rb = 0; rb < 2; ++rb)
#pragma unroll
        for (int kc = 0; kc < 4; ++kc)
#pragma unroll
            for (int jp = 0; jp < 4; ++jp)
                xf[rb][kc].u4[jp] = pkbf(xr[(rb * 4 + kc) * 8 + 2 * jp],
                                         xr[(rb * 4 + kc) * 8 + 2 * jp + 1]);

    f32x16 acc[2][2];   // Y tiles: [cb over ac][nb2 over de]
#pragma unroll
    for (int a = 0; a < 2; ++a)
#pragma unroll
        for (int c = 0; c < 2; ++c)
#pragma unroll
            for (int e = 0; e < 16; ++e)
                acc[a][c][e] = 0.f;

    // ---- p-loop: pure LDS reads + MFMA + VALU repack. No vmem, no barriers.
#pragma unroll 1
    for (int p = 0; p < 8; ++p) {
        Frag8 af[2][4];
#pragma unroll
        for (int t = 0; t < 2; ++t)
#pragma unroll
            for (int kc = 0; kc < 4; ++kc)
                af[t][kc].v = *(const bf16x8*)(LA + p * 4096 + ((t * 4 + kc) * 64 + lane) * 8);
#pragma unroll
        for (int rb = 0; rb < 2; ++rb) {       // rb: kl block (contraction of step B)
            Frag8 wfr[2][2];                   // wf[nb2][kk = 2rb, 2rb+1]
#pragma unroll
            for (int t = 0; t < 2; ++t)
#pragma unroll
                for (int kk = 0; kk < 2; ++kk)
                    wfr[t][kk].v = *(const bf16x8*)(LW + p * 4096 + ((t * 4 + 2 * rb + kk) * 64 + lane) * 8);
#pragma unroll
            for (int cb = 0; cb < 2; ++cb) {   // cb: ac block
                // ---- Step A: T^T tile (kl rows rb*32.., ac cols cb*32..)
                f32x16 t;
#pragma unroll
                for (int e = 0; e < 16; ++e) t[e] = 0.f;
#pragma unroll
                for (int kc = 0; kc < 4; ++kc)
                    t = __builtin_amdgcn_mfma_f32_32x32x16_bf16(xf[rb][kc].v, af[cb][kc].v, t, 0, 0, 0);
                // ---- Repack C/D -> two step-B A-operand frags, in-register.
                unsigned int wd[8];
#pragma unroll
                for (int h = 0; h < 8; ++h) wd[h] = pkbf(t[2 * h], t[2 * h + 1]);
                auto s02 = __builtin_amdgcn_permlane32_swap(wd[0], wd[2], false, false);
                auto s13 = __builtin_amdgcn_permlane32_swap(wd[1], wd[3], false, false);
                auto s46 = __builtin_amdgcn_permlane32_swap(wd[4], wd[6], false, false);
                auto s57 = __builtin_amdgcn_permlane32_swap(wd[5], wd[7], false, false);
                Frag8 tb0, tb1;
                tb0.u4[0] = s02[0]; tb0.u4[1] = s13[0]; tb0.u4[2] = s02[1]; tb0.u4[3] = s13[1];
                tb1.u4[0] = s46[0]; tb1.u4[1] = s57[0]; tb1.u4[2] = s46[1]; tb1.u4[3] = s57[1];
                // ---- Step B: Y[ac][de] += T[ac][kl] * W[kl][de]
                acc[cb][0] = __builtin_amdgcn_mfma_f32_32x32x16_bf16(tb0.v, wfr[0][0].v, acc[cb][0], 0, 0, 0);
                acc[cb][0] = __builtin_amdgcn_mfma_f32_32x32x16_bf16(tb1.v, wfr[0][1].v, acc[cb][0], 0, 0, 0);
                acc[cb][1] = __builtin_amdgcn_mfma_f32_32x32x16_bf16(tb0.v, wfr[1][0].v, acc[cb][1], 0, 0, 0);
                acc[cb][1] = __builtin_amdgcn_mfma_f32_32x32x16_bf16(tb1.v, wfr[1][1].v, acc[cb][1], 0, 0, 0);
            }
        }
    }

    // ---- Epilogue: direct coalesced stores. C/D: col de = nb2*32+l31,
    // row ac = cb*32 + (r&3)+8*(r>>2)+4*hi. Bias from LDS (lgkm, not vmcnt).
    float* ob = out + ((size_t)b << 12);
#pragma unroll
    for (int cb = 0; cb < 2; ++cb)
#pragma unroll
        for (int nb2 = 0; nb2 < 2; ++nb2)
#pragma unroll
            for (int r = 0; r < 16; ++r) {
                int ac = cb * 32 + (r & 3) + 8 * (r >> 2) + 4 * hi;
                int o  = ac * 64 + nb2 * 32 + l31;
                ob[o] = acc[cb][nb2][r] + sBias[o];
            }
}

extern "C" void kernel_launch(void* const* d_in, const int* in_sizes, int n_in,
                              void* d_out, int out_size, void* d_ws, size_t ws_size,
                              hipStream_t stream) {
    const float* x    = (const float*)d_in[0];
    const float* F0   = (const float*)d_in[1];
    const float* F1   = (const float*)d_in[2];
    const float* F2   = (const float*)d_in[3];
    const float* F3   = (const float*)d_in[4];
    const float* CL   = (const float*)d_in[5];
    const float* CR   = (const float*)d_in[6];
    const float* bias = (const float*)d_in[7];
    float* out = (float*)d_out;
    unsigned short* frags = (unsigned short*)d_ws;   // 128 KB

    const int B = in_sizes[0] / 4096;   // 4096

    ht_precompute<<<16, 256, 0, stream>>>(F0, F1, F2, F3, CL, CR, frags);
    ht_main<<<B / 8, 512, 0, stream>>>(x, frags, bias, out);
}